// Round 3
// baseline (26844.580 us; speedup 1.0000x reference)
//
#include <hip/hip_runtime.h>
#include <hip/hip_bf16.h>

// GRU-imputation scan, persistent-kernel. ROUND 3: inputs/outputs are FLOAT32
// (per the jnp.float32 reference; bf16 misread explains rounds 1-2 NaN).
// Compute: f32->bf16 truncation into MFMA fragments on the fly; h/comp/out in f32.
// B=128 T=128 D=128 H=1024 L=3.
// Per step t: L0 (layer0: input=comp, hidden=hA -> hB), L1 (hB->hC),
// L2 (hC->hA, + h_final at t=127), IC (imp/comp for t<127).
// Grid barrier: two-level atomic tree (8 leaves x 32 blocks), agent scope.

typedef unsigned int u32;
typedef __attribute__((ext_vector_type(8))) short v8bf;   // 8 x bf16 (4 VGPRs)
typedef __attribute__((ext_vector_type(4))) float v4f;    // MFMA C/D
typedef __attribute__((ext_vector_type(4))) u32 v4u;

#define SC __HIP_MEMORY_SCOPE_AGENT

__device__ __forceinline__ float sigm(float x){ return 1.f/(1.f + __expf(-x)); }
__device__ __forceinline__ float tanh_(float x){
  float a = fminf(fmaxf(x, -15.f), 15.f);
  float t = __expf(2.f*a);
  return (t-1.f)/(t+1.f);
}

// load 8 consecutive f32 (32B, aligned) and truncate to bf16 fragment
__device__ __forceinline__ v8bf cvt8(const float* p){
  const v4u a = *reinterpret_cast<const v4u*>(p);
  const v4u b = *reinterpret_cast<const v4u*>(p + 4);
  v8bf r;
  #pragma unroll
  for (int i=0;i<4;i++){ r[i]   = (short)(a[i] >> 16); }
  #pragma unroll
  for (int i=0;i<4;i++){ r[4+i] = (short)(b[i] >> 16); }
  return r;
}

// ---------------- grid barrier ----------------
// bar[leaf*32] for leaf 0..7 (128B-padded lines), bar[256]=root, bar[288]=epoch
__device__ __forceinline__ void gbar(u32* bar, int leaf, u32 target){
  __syncthreads();
  if (threadIdx.x == 0){
    __threadfence();  // publish this WG's global stores (agent scope)
    u32 lf = __hip_atomic_fetch_add(&bar[leaf*32], 1u, __ATOMIC_SEQ_CST, SC);
    if (lf == 31u){
      u32 rt = __hip_atomic_fetch_add(&bar[256], 1u, __ATOMIC_SEQ_CST, SC);
      if (rt == 7u){
        #pragma unroll
        for (int i=0;i<8;i++) __hip_atomic_store(&bar[i*32], 0u, __ATOMIC_RELAXED, SC);
        __hip_atomic_store(&bar[256], 0u, __ATOMIC_RELAXED, SC);
        __hip_atomic_fetch_add(&bar[288], 1u, __ATOMIC_SEQ_CST, SC);
      }
    }
    while (__hip_atomic_load(&bar[288], __ATOMIC_SEQ_CST, SC) < target){
      __builtin_amdgcn_s_sleep(2);
    }
    __threadfence();  // acquire side
  }
  __syncthreads();
}

// ---------------- init (once per call) ----------------
// h3 = hA|hB|hC contiguous (3*131072 f32). comp = x[:,0,:].
__global__ void init_k(u32* __restrict__ bar, float* __restrict__ h3,
                       float* __restrict__ comp, const float* __restrict__ x){
  int tid = blockIdx.x*256 + threadIdx.x;          // 1536*256 = 393216
  if (tid < 1024) bar[tid] = 0u;
  if (tid < 16384) comp[tid] = x[(size_t)(tid>>7)*16384 + (tid&127)];
  h3[tid] = 0.f;
}

// ---------------- upper layer (input == hidden == src) ----------------
// wave0: r pre-act (Wih rows [0,1024) + Whh rows [0,1024) chained into one acc)
// wave1: z pre-act (rows [1024,2048))
// wave2: i_n (Wih rows [2048,3072))   wave3: h_n (Whh rows [2048,3072))
__device__ __forceinline__ void upper_phase(
    const float* __restrict__ src, float* __restrict__ dst,
    const float* __restrict__ Wih, const float* __restrict__ Whh,
    const float* __restrict__ bih, const float* __restrict__ bhh,
    int j, int rowbase, int wave, int lane, float* smem, float* out_h)
{
  const int l15 = lane & 15, quad = lane >> 4;
  v4f acc0 = {0.f,0.f,0.f,0.f}, acc1 = {0.f,0.f,0.f,0.f};
  const float* a0 = src + (size_t)(rowbase + l15)*1024 + quad*8;
  if (wave < 2){
    const size_t ro = (size_t)(wave*1024 + j*16 + l15)*1024 + quad*8;
    const float* wi = Wih + ro;
    const float* wh = Whh + ro;
    #pragma unroll 2
    for (int kk=0; kk<32; ++kk){
      v8bf af0 = cvt8(a0 + kk*32);
      v8bf af1 = cvt8(a0 + 16*1024 + kk*32);
      v8bf w0  = cvt8(wi + kk*32);
      v8bf w1  = cvt8(wh + kk*32);
      acc0 = __builtin_amdgcn_mfma_f32_16x16x32_bf16(af0, w0, acc0, 0,0,0);
      acc0 = __builtin_amdgcn_mfma_f32_16x16x32_bf16(af0, w1, acc0, 0,0,0);
      acc1 = __builtin_amdgcn_mfma_f32_16x16x32_bf16(af1, w0, acc1, 0,0,0);
      acc1 = __builtin_amdgcn_mfma_f32_16x16x32_bf16(af1, w1, acc1, 0,0,0);
    }
  } else {
    const float* w = (wave == 2 ? Wih : Whh) + (size_t)(2048 + j*16 + l15)*1024 + quad*8;
    #pragma unroll 2
    for (int kk=0; kk<32; ++kk){
      v8bf af0 = cvt8(a0 + kk*32);
      v8bf af1 = cvt8(a0 + 16*1024 + kk*32);
      v8bf w0  = cvt8(w + kk*32);
      acc0 = __builtin_amdgcn_mfma_f32_16x16x32_bf16(af0, w0, acc0, 0,0,0);
      acc1 = __builtin_amdgcn_mfma_f32_16x16x32_bf16(af1, w0, acc1, 0,0,0);
    }
  }
  #pragma unroll
  for (int r=0;r<4;r++){
    smem[((wave*32) + quad*4 + r)*16 + l15]      = acc0[r];
    smem[((wave*32) + 16 + quad*4 + r)*16 + l15] = acc1[r];
  }
  __syncthreads();
  const int tid = threadIdx.x;
  for (int e = tid; e < 512; e += 256){
    int rl = e>>4, c = e&15;
    int row = rowbase + rl, col = j*16 + c;
    float pr  = smem[(0*32+rl)*16+c] + bih[col]      + bhh[col];
    float pz  = smem[(1*32+rl)*16+c] + bih[1024+col] + bhh[1024+col];
    float pin = smem[(2*32+rl)*16+c] + bih[2048+col];
    float phn = smem[(3*32+rl)*16+c] + bhh[2048+col];
    float rg = sigm(pr);
    float zg = sigm(pz);
    float nv = tanh_(pin + rg*phn);
    float hp = src[(size_t)row*1024 + col];
    float hv = (1.f - zg)*nv + zg*hp;
    dst[(size_t)row*1024 + col] = hv;
    if (out_h) out_h[(size_t)row*1024 + col] = hv;
  }
}

// ---------------- main persistent kernel ----------------
__global__ __launch_bounds__(256, 1) void gru_main(
  const float* __restrict__ x, const float* __restrict__ masks,
  const float* __restrict__ Wih0, const float* __restrict__ Whh0,
  const float* __restrict__ bih0, const float* __restrict__ bhh0,
  const float* __restrict__ WihR, const float* __restrict__ WhhR,
  const float* __restrict__ bihR, const float* __restrict__ bhhR,
  const float* __restrict__ Wp,   const float* __restrict__ bp,
  float* hA, float* hB, float* hC, float* comp,
  u32* bar, float* out)
{
  const int tid  = threadIdx.x;
  const int lane = tid & 63;
  const int wave = tid >> 6;
  const int l15  = lane & 15;
  const int quad = lane >> 4;
  const int bid  = blockIdx.x;
  const int leaf = bid & 7;
  const int slot = bid >> 3;               // 0..31
  const int j    = leaf*8 + (slot >> 2);   // column tile 0..63
  const int rowbase = (slot & 3) * 32;     // msplit=4
  __shared__ float smem[6*32*16];          // 12 KB
  u32 bc = 0;

  #pragma unroll 1
  for (int t = 0; t < 128; ++t){
    // ---------- L0: hB = GRU0(input=comp, hidden=hA) ----------
    {
      if (wave < 3){
        // gh strip, gate g=wave: hA @ Whh0[g*1024+n, :].T, K=1024
        v4f acc0 = {0.f,0.f,0.f,0.f}, acc1 = {0.f,0.f,0.f,0.f};
        const float* w  = Whh0 + (size_t)(wave*1024 + j*16 + l15)*1024 + quad*8;
        const float* a0 = hA + (size_t)(rowbase + l15)*1024 + quad*8;
        #pragma unroll 2
        for (int kk=0; kk<32; ++kk){
          v8bf af0 = cvt8(a0 + kk*32);
          v8bf af1 = cvt8(a0 + 16*1024 + kk*32);
          v8bf w0  = cvt8(w + kk*32);
          acc0 = __builtin_amdgcn_mfma_f32_16x16x32_bf16(af0, w0, acc0, 0,0,0);
          acc1 = __builtin_amdgcn_mfma_f32_16x16x32_bf16(af1, w0, acc1, 0,0,0);
        }
        #pragma unroll
        for (int r=0;r<4;r++){
          smem[((wave*32) + quad*4 + r)*16 + l15]      = acc0[r];
          smem[((wave*32) + 16 + quad*4 + r)*16 + l15] = acc1[r];
        }
      } else {
        // gi strips: comp @ Wih0[g*1024+n, :].T, K=128, all 3 gates on wave 3
        v4f ax[3][2];
        #pragma unroll
        for (int g=0;g<3;g++){ ax[g][0] = (v4f){0.f,0.f,0.f,0.f}; ax[g][1] = (v4f){0.f,0.f,0.f,0.f}; }
        const float* a0 = comp + (size_t)(rowbase + l15)*128 + quad*8;
        #pragma unroll
        for (int kk=0; kk<4; ++kk){
          v8bf af0 = cvt8(a0 + kk*32);
          v8bf af1 = cvt8(a0 + 16*128 + kk*32);
          #pragma unroll
          for (int g=0; g<3; ++g){
            v8bf w0 = cvt8(Wih0 + (size_t)(g*1024 + j*16 + l15)*128 + quad*8 + kk*32);
            ax[g][0] = __builtin_amdgcn_mfma_f32_16x16x32_bf16(af0, w0, ax[g][0], 0,0,0);
            ax[g][1] = __builtin_amdgcn_mfma_f32_16x16x32_bf16(af1, w0, ax[g][1], 0,0,0);
          }
        }
        #pragma unroll
        for (int g=0; g<3; ++g){
          #pragma unroll
          for (int r=0;r<4;r++){
            smem[(((3+g)*32) + quad*4 + r)*16 + l15]      = ax[g][0][r];
            smem[(((3+g)*32) + 16 + quad*4 + r)*16 + l15] = ax[g][1][r];
          }
        }
      }
      __syncthreads();
      for (int e = tid; e < 512; e += 256){
        int rl = e>>4, c = e&15;
        int row = rowbase + rl, col = j*16 + c;
        float gh_r = smem[(0*32+rl)*16+c] + bhh0[col];
        float gh_z = smem[(1*32+rl)*16+c] + bhh0[1024+col];
        float gh_n = smem[(2*32+rl)*16+c] + bhh0[2048+col];
        float gi_r = smem[(3*32+rl)*16+c] + bih0[col];
        float gi_z = smem[(4*32+rl)*16+c] + bih0[1024+col];
        float gi_n = smem[(5*32+rl)*16+c] + bih0[2048+col];
        float rg = sigm(gi_r + gh_r);
        float zg = sigm(gi_z + gh_z);
        float nv = tanh_(gi_n + rg*gh_n);
        float hp = hA[(size_t)row*1024 + col];
        hB[(size_t)row*1024 + col] = (1.f - zg)*nv + zg*hp;
      }
      gbar(bar, leaf, ++bc);
    }

    // ---------- L1: hC = GRU1(hB, hB) ----------
    upper_phase(hB, hC, WihR, WhhR, bihR, bhhR,
                j, rowbase, wave, lane, smem, nullptr);
    gbar(bar, leaf, ++bc);

    // ---------- L2: hA = GRU2(hC, hC) (+ h_final at t==127) ----------
    upper_phase(hC, hA, WihR + 3145728, WhhR + 3145728, bihR + 3072, bhhR + 3072,
                j, rowbase, wave, lane, smem, (t == 127) ? out : nullptr);
    gbar(bar, leaf, ++bc);

    // ---------- IC: imputed/completed outputs (t < 127) ----------
    if (t != 127){
      if (bid < 32){
        const int jj  = bid >> 2;           // imp column tile 0..7 (D=128)
        const int rb2 = (bid & 3) * 32;
        v4f p0 = {0.f,0.f,0.f,0.f}, p1 = {0.f,0.f,0.f,0.f};
        const float* a0 = hA + (size_t)(rb2 + l15)*1024 + wave*256 + quad*8;
        const float* wp = Wp + (size_t)(jj*16 + l15)*1024 + wave*256 + quad*8;
        #pragma unroll
        for (int i=0;i<8;i++){
          v8bf wf  = cvt8(wp + i*32);
          v8bf af0 = cvt8(a0 + i*32);
          v8bf af1 = cvt8(a0 + 16*1024 + i*32);
          p0 = __builtin_amdgcn_mfma_f32_16x16x32_bf16(af0, wf, p0, 0,0,0);
          p1 = __builtin_amdgcn_mfma_f32_16x16x32_bf16(af1, wf, p1, 0,0,0);
        }
        #pragma unroll
        for (int r=0;r<4;r++){
          smem[((wave*32) + quad*4 + r)*16 + l15]      = p0[r];
          smem[((wave*32) + 16 + quad*4 + r)*16 + l15] = p1[r];
        }
        __syncthreads();
        for (int e = tid; e < 512; e += 256){
          int rl = e>>4, c = e&15;
          int row = rb2 + rl, d = jj*16 + c;
          float imp = smem[(0*32+rl)*16+c] + smem[(1*32+rl)*16+c]
                    + smem[(2*32+rl)*16+c] + smem[(3*32+rl)*16+c] + bp[d];
          float m  = masks[row*128 + t];
          float xv = x[((size_t)row*128 + t)*128 + d];
          float cv = m*xv + (1.f - m)*imp;
          size_t o = ((size_t)row*127 + t)*128 + d;
          out[131072 + o]  = cv;    // completed
          out[2211840 + o] = imp;   // imputed
          comp[row*128 + d] = cv;   // next step's layer-0 input
        }
      }
      gbar(bar, leaf, ++bc);
    }
  }
}

// ---------------- host ----------------
extern "C" void kernel_launch(void* const* d_in, const int* in_sizes, int n_in,
                              void* d_out, int out_size, void* d_ws, size_t ws_size,
                              hipStream_t stream)
{
  (void)in_sizes; (void)n_in; (void)out_size; (void)ws_size;
  const float* x     = (const float*)d_in[0];
  const float* masks = (const float*)d_in[1];
  const float* Wih0  = (const float*)d_in[2];
  const float* Whh0  = (const float*)d_in[3];
  const float* bih0  = (const float*)d_in[4];
  const float* bhh0  = (const float*)d_in[5];
  const float* WihR  = (const float*)d_in[6];
  const float* WhhR  = (const float*)d_in[7];
  const float* bihR  = (const float*)d_in[8];
  const float* bhhR  = (const float*)d_in[9];
  const float* Wp    = (const float*)d_in[10];
  const float* bp    = (const float*)d_in[11];
  float* out = (float*)d_out;

  // workspace: bar u32[1024] | hA | hB | hC (f32 131072 each) | comp (f32 16384)
  u32*   bar  = (u32*)d_ws;
  float* hA   = (float*)((char*)d_ws + 4096);
  float* hB   = hA + 131072;
  float* hC   = hB + 131072;
  float* comp = hC + 131072;

  hipLaunchKernelGGL(init_k,  dim3(1536), dim3(256), 0, stream, bar, hA, comp, x);
  hipLaunchKernelGGL(gru_main, dim3(256), dim3(256), 0, stream,
      x, masks, Wih0, Whh0, bih0, bhh0, WihR, WhhR, bihR, bhhR, Wp, bp,
      hA, hB, hC, comp, bar, out);
}

// Round 4
// 10335.044 us; speedup vs baseline: 2.5974x; 2.5974x over previous
//
#include <hip/hip_runtime.h>
#include <hip/hip_bf16.h>

// GRU-imputation scan (B=128,T=128,D=128,H=1024,L=3), f32 in/out.
// Round 4: persistent kernel, 1024 threads/block (16 waves -> 4x MLP),
// bf16-packed fragment-ordered weights (r/z pre-summed for upper layers),
// bf16 h/comp state, relaxed-spin barrier (1 cache-maintenance op per
// block per barrier instead of per poll).
// Fallback to the round-3 kernel if ws_size < ~24 MB.

typedef __hip_bfloat16 bf16;
typedef unsigned int u32;
typedef __attribute__((ext_vector_type(8))) short v8bf;   // 8 x bf16
typedef __attribute__((ext_vector_type(4))) float v4f;    // MFMA C/D
typedef __attribute__((ext_vector_type(4))) u32 v4u;

#define SC __HIP_MEMORY_SCOPE_AGENT

__device__ __forceinline__ float bf2f(bf16 v){ return __bfloat162float(v); }
__device__ __forceinline__ bf16 f2bf(float v){ return __float2bfloat16(v); }  // RNE
__device__ __forceinline__ float sigm(float x){ return 1.f/(1.f + __expf(-x)); }
__device__ __forceinline__ float tanh_(float x){
  float a = fminf(fmaxf(x, -15.f), 15.f);
  float t = __expf(2.f*a);
  return (t-1.f)/(t+1.f);
}
__device__ __forceinline__ v8bf ldv(const bf16* p){ return *reinterpret_cast<const v8bf*>(p); }

// ---------------- fast grid barrier ----------------
// bar[leaf*32] leaf 0..7 (128B lines), bar[256]=root, bar[288]=epoch.
// RELEASE arrival (drains+wbl2 once), RELAXED spin (no per-poll cache ops),
// single acquire fence after spin.
__device__ __forceinline__ void gbar(u32* bar, int leaf, u32 target){
  __syncthreads();
  if (threadIdx.x == 0){
    u32 lf = __hip_atomic_fetch_add(&bar[leaf*32], 1u, __ATOMIC_RELEASE, SC);
    if (lf == 31u){
      u32 rt = __hip_atomic_fetch_add(&bar[256], 1u, __ATOMIC_RELEASE, SC);
      if (rt == 7u){
        #pragma unroll
        for (int i=0;i<8;i++) __hip_atomic_store(&bar[i*32], 0u, __ATOMIC_RELAXED, SC);
        __hip_atomic_store(&bar[256], 0u, __ATOMIC_RELAXED, SC);
        __hip_atomic_fetch_add(&bar[288], 1u, __ATOMIC_RELEASE, SC);
      }
    }
    while (__hip_atomic_load(&bar[288], __ATOMIC_RELAXED, SC) < target){
      __builtin_amdgcn_s_sleep(1);
    }
    __threadfence();   // acquire: one L2 inv so we see other blocks' h stores
  }
  __syncthreads();
}

// =================================================================
// Packing kernels (once per call). Fragment unit = 64 lanes x 8 bf16.
// lane's 8 elems = W[row(j,lane&15)][kk*32 + ((lane>>4)&3)*8 + e]
// =================================================================

// packU: u = ((l*4+s)*64 + j)*32 + kk ; s: 0=r(sum),1=z(sum),2=i_n(Wih),3=h_n(Whh)
__global__ void pack_upper_k(const float* __restrict__ Wih, const float* __restrict__ Whh,
                             bf16* __restrict__ dst){
  int tid = blockIdx.x*256 + threadIdx.x;          // 1,048,576
  int lane = tid & 63;
  int u    = tid >> 6;
  int kk   = u & 31;
  int j    = (u >> 5) & 63;
  int s    = (u >> 11) & 3;
  int l    = u >> 13;
  int n    = j*16 + (lane & 15);
  int k    = kk*32 + ((lane>>4)&3)*8;
  int row  = (s==0) ? n : (s==1 ? 1024+n : 2048+n);
  size_t src = ((size_t)l*3072 + row)*1024 + k;
  size_t o = (size_t)tid*8;
  #pragma unroll
  for (int e=0;e<8;e++){
    float v;
    if (s < 2)      v = Wih[src+e] + Whh[src+e];
    else if (s==2)  v = Wih[src+e];
    else            v = Whh[src+e];
    dst[o+e] = f2bf(v);
  }
}

// packL0h: u = (g*64 + j)*32 + kk, from Whh0 (3072x1024)
__global__ void pack_l0h_k(const float* __restrict__ Whh0, bf16* __restrict__ dst){
  int tid = blockIdx.x*256 + threadIdx.x;          // 393,216
  int lane = tid & 63;
  int u  = tid >> 6;
  int kk = u & 31;
  int j  = (u >> 5) & 63;
  int g  = u >> 11;
  int row = g*1024 + j*16 + (lane&15);
  int k   = kk*32 + ((lane>>4)&3)*8;
  size_t src = (size_t)row*1024 + k;
  size_t o = (size_t)tid*8;
  #pragma unroll
  for (int e=0;e<8;e++) dst[o+e] = f2bf(Whh0[src+e]);
}

// packL0x: u = (g*64 + j)*4 + kk, from Wih0 (3072x128)
__global__ void pack_l0x_k(const float* __restrict__ Wih0, bf16* __restrict__ dst){
  int tid = blockIdx.x*256 + threadIdx.x;          // 49,152
  int lane = tid & 63;
  int u  = tid >> 6;
  int kk = u & 3;
  int j  = (u >> 2) & 63;
  int g  = u >> 8;
  int row = g*1024 + j*16 + (lane&15);
  int k   = kk*32 + ((lane>>4)&3)*8;
  size_t src = (size_t)row*128 + k;
  size_t o = (size_t)tid*8;
  #pragma unroll
  for (int e=0;e<8;e++) dst[o+e] = f2bf(Wih0[src+e]);
}

// packImp: u = jj*32 + kk, from Wp (128x1024)
__global__ void pack_imp_k(const float* __restrict__ Wp, bf16* __restrict__ dst){
  int tid = blockIdx.x*256 + threadIdx.x;          // 16,384
  int lane = tid & 63;
  int u  = tid >> 6;
  int kk = u & 31;
  int jj = u >> 5;
  int row = jj*16 + (lane&15);
  int k   = kk*32 + ((lane>>4)&3)*8;
  size_t src = (size_t)row*1024 + k;
  size_t o = (size_t)tid*8;
  #pragma unroll
  for (int e=0;e<8;e++) dst[o+e] = f2bf(Wp[src+e]);
}

// init: bar=0, h(bf16)=0, comp(bf16)=x[:,0,:]
__global__ void init_pk(u32* __restrict__ bar, bf16* __restrict__ h3,
                        bf16* __restrict__ comp, const float* __restrict__ x){
  int tid = blockIdx.x*256 + threadIdx.x;          // 393,216
  if (tid < 1024) bar[tid] = 0u;
  if (tid < 16384) comp[tid] = f2bf(x[(size_t)(tid>>7)*16384 + (tid&127)]);
  h3[tid] = f2bf(0.f);
}

// =================================================================
// Main persistent kernel: 256 blocks x 1024 threads (16 waves).
// Block: j = column tile (16 cols), rowbase = 32-row slice (msplit=4).
// Upper phase: wave w -> strip s=w&3 (r,z,in,hn), ksec=w>>2 (K=256 slice).
// =================================================================

__device__ __forceinline__ void upper_phase(
    const bf16* __restrict__ src, bf16* __restrict__ dst,
    const bf16* __restrict__ packL,   // this layer's packed strips
    const float* __restrict__ bih, const float* __restrict__ bhh,
    int j, int rowbase, int wave, int lane, float* lds, float* out_h)
{
  const int l15 = lane & 15, quad = lane >> 4;
  const int s = wave & 3, ksec = wave >> 2;
  v4f acc0 = {0.f,0.f,0.f,0.f}, acc1 = {0.f,0.f,0.f,0.f};
  const bf16* wp = packL + ((size_t)((s*64 + j)*32 + ksec*8))*512 + lane*8;
  const bf16* a0 = src + (size_t)(rowbase + l15)*1024 + ksec*256 + quad*8;
  #pragma unroll
  for (int i=0; i<8; ++i){
    v8bf wf  = ldv(wp + i*512);
    v8bf af0 = ldv(a0 + i*32);
    v8bf af1 = ldv(a0 + 16*1024 + i*32);
    acc0 = __builtin_amdgcn_mfma_f32_16x16x32_bf16(af0, wf, acc0, 0,0,0);
    acc1 = __builtin_amdgcn_mfma_f32_16x16x32_bf16(af1, wf, acc1, 0,0,0);
  }
  #pragma unroll
  for (int r=0;r<4;r++){
    lds[(wave*32 + quad*4 + r)*16 + l15]      = acc0[r];
    lds[(wave*32 + 16 + quad*4 + r)*16 + l15] = acc1[r];
  }
  __syncthreads();
  const int tid = threadIdx.x;
  if (tid < 512){
    int rl = tid>>4, c = tid&15;
    int row = rowbase + rl, col = j*16 + c;
    float p0=0.f,p1=0.f,p2=0.f,p3=0.f;
    #pragma unroll
    for (int q=0;q<4;q++){
      p0 += lds[(q*4+0)*512 + tid];
      p1 += lds[(q*4+1)*512 + tid];
      p2 += lds[(q*4+2)*512 + tid];
      p3 += lds[(q*4+3)*512 + tid];
    }
    float rg = sigm(p0 + bih[col]      + bhh[col]);
    float zg = sigm(p1 + bih[1024+col] + bhh[1024+col]);
    float nv = tanh_(p2 + bih[2048+col] + rg*(p3 + bhh[2048+col]));
    float hp = bf2f(src[(size_t)row*1024 + col]);
    float hv = (1.f - zg)*nv + zg*hp;
    dst[(size_t)row*1024 + col] = f2bf(hv);
    if (out_h) out_h[(size_t)row*1024 + col] = hv;
  }
}

__global__ __launch_bounds__(1024) void gru_pk(
  const float* __restrict__ x, const float* __restrict__ masks,
  const float* __restrict__ bih0, const float* __restrict__ bhh0,
  const float* __restrict__ bihR, const float* __restrict__ bhhR,
  const float* __restrict__ bp,
  const bf16* __restrict__ packU, const bf16* __restrict__ packL0h,
  const bf16* __restrict__ packL0x, const bf16* __restrict__ packImp,
  bf16* hA, bf16* hB, bf16* hC, bf16* comp,
  u32* bar, float* out)
{
  const int tid  = threadIdx.x;
  const int lane = tid & 63;
  const int wave = tid >> 6;           // 0..15
  const int l15  = lane & 15;
  const int quad = lane >> 4;
  const int bid  = blockIdx.x;
  const int leaf = bid & 7;
  const int slot = bid >> 3;           // 0..31
  const int j    = leaf*8 + (slot >> 2);   // 0..63
  const int rowbase = (slot & 3) * 32;
  __shared__ float lds[16*512];        // 32 KB partial staging
  u32 bc = 0;

  #pragma unroll 1
  for (int t = 0; t < 128; ++t){
    // ---------- L0: hB = GRU0(input=comp, hidden=hA) ----------
    {
      if (wave < 12){
        const int s = wave % 3, ksec = wave / 3;   // gh strip s, K-slice 256
        v4f acc0 = {0.f,0.f,0.f,0.f}, acc1 = {0.f,0.f,0.f,0.f};
        const bf16* wp = packL0h + ((size_t)((s*64 + j)*32 + ksec*8))*512 + lane*8;
        const bf16* a0 = hA + (size_t)(rowbase + l15)*1024 + ksec*256 + quad*8;
        #pragma unroll
        for (int i=0; i<8; ++i){
          v8bf wf  = ldv(wp + i*512);
          v8bf af0 = ldv(a0 + i*32);
          v8bf af1 = ldv(a0 + 16*1024 + i*32);
          acc0 = __builtin_amdgcn_mfma_f32_16x16x32_bf16(af0, wf, acc0, 0,0,0);
          acc1 = __builtin_amdgcn_mfma_f32_16x16x32_bf16(af1, wf, acc1, 0,0,0);
        }
        #pragma unroll
        for (int r=0;r<4;r++){
          lds[(wave*32 + quad*4 + r)*16 + l15]      = acc0[r];
          lds[(wave*32 + 16 + quad*4 + r)*16 + l15] = acc1[r];
        }
      } else if (wave < 15){
        const int g = wave - 12;                    // gi strip g, full K=128
        v4f acc0 = {0.f,0.f,0.f,0.f}, acc1 = {0.f,0.f,0.f,0.f};
        const bf16* wp = packL0x + ((size_t)((g*64 + j)*4))*512 + lane*8;
        const bf16* a0 = comp + (size_t)(rowbase + l15)*128 + quad*8;
        #pragma unroll
        for (int i=0; i<4; ++i){
          v8bf wf  = ldv(wp + i*512);
          v8bf af0 = ldv(a0 + i*32);
          v8bf af1 = ldv(a0 + 16*128 + i*32);
          acc0 = __builtin_amdgcn_mfma_f32_16x16x32_bf16(af0, wf, acc0, 0,0,0);
          acc1 = __builtin_amdgcn_mfma_f32_16x16x32_bf16(af1, wf, acc1, 0,0,0);
        }
        #pragma unroll
        for (int r=0;r<4;r++){
          lds[(wave*32 + quad*4 + r)*16 + l15]      = acc0[r];
          lds[(wave*32 + 16 + quad*4 + r)*16 + l15] = acc1[r];
        }
      }
      __syncthreads();
      if (tid < 512){
        int rl = tid>>4, c = tid&15;
        int row = rowbase + rl, col = j*16 + c;
        float ghr=0.f, ghz=0.f, ghn=0.f;
        #pragma unroll
        for (int q=0;q<4;q++){
          ghr += lds[(q*3+0)*512 + tid];
          ghz += lds[(q*3+1)*512 + tid];
          ghn += lds[(q*3+2)*512 + tid];
        }
        float gir = lds[12*512 + tid];
        float giz = lds[13*512 + tid];
        float gin = lds[14*512 + tid];
        float rg = sigm(gir + bih0[col]      + ghr + bhh0[col]);
        float zg = sigm(giz + bih0[1024+col] + ghz + bhh0[1024+col]);
        float nv = tanh_(gin + bih0[2048+col] + rg*(ghn + bhh0[2048+col]));
        float hp = bf2f(hA[(size_t)row*1024 + col]);
        hB[(size_t)row*1024 + col] = f2bf((1.f - zg)*nv + zg*hp);
      }
      gbar(bar, leaf, ++bc);
    }

    // ---------- L1: hC = GRU1(hB, hB) ----------
    upper_phase(hB, hC, packU, bihR, bhhR, j, rowbase, wave, lane, lds, nullptr);
    gbar(bar, leaf, ++bc);

    // ---------- L2: hA = GRU2(hC, hC) (+ h_final f32 at t==127) ----------
    upper_phase(hC, hA, packU + (size_t)4*64*32*512, bihR + 3072, bhhR + 3072,
                j, rowbase, wave, lane, lds, (t == 127) ? out : nullptr);
    gbar(bar, leaf, ++bc);

    // ---------- IC: imputed/completed (t < 127) ----------
    if (t != 127){
      if (bid < 32){
        const int jj  = bid >> 2;          // d-tile 0..7
        const int rb2 = (bid & 3) * 32;
        v4f acc0 = {0.f,0.f,0.f,0.f}, acc1 = {0.f,0.f,0.f,0.f};
        const bf16* wp = packImp + ((size_t)(jj*32 + wave*2))*512 + lane*8;
        const bf16* a0 = hA + (size_t)(rb2 + l15)*1024 + wave*64 + quad*8;
        #pragma unroll
        for (int i=0; i<2; ++i){
          v8bf wf  = ldv(wp + i*512);
          v8bf af0 = ldv(a0 + i*32);
          v8bf af1 = ldv(a0 + 16*1024 + i*32);
          acc0 = __builtin_amdgcn_mfma_f32_16x16x32_bf16(af0, wf, acc0, 0,0,0);
          acc1 = __builtin_amdgcn_mfma_f32_16x16x32_bf16(af1, wf, acc1, 0,0,0);
        }
        #pragma unroll
        for (int r=0;r<4;r++){
          lds[(wave*32 + quad*4 + r)*16 + l15]      = acc0[r];
          lds[(wave*32 + 16 + quad*4 + r)*16 + l15] = acc1[r];
        }
        __syncthreads();
        if (tid < 512){
          int rl = tid>>4, c = tid&15;
          int row = rb2 + rl, d = jj*16 + c;
          float imp = bp[d];
          #pragma unroll
          for (int w2=0; w2<16; ++w2) imp += lds[w2*512 + tid];
          float m  = masks[row*128 + t];
          float xv = x[((size_t)row*128 + t)*128 + d];
          float cv = m*xv + (1.f - m)*imp;
          size_t o = ((size_t)row*127 + t)*128 + d;
          out[131072 + o]  = cv;    // completed
          out[2211840 + o] = imp;   // imputed
          comp[row*128 + d] = f2bf(cv);
        }
      }
      gbar(bar, leaf, ++bc);
    }
  }
}

// =================================================================
// FALLBACK (round-3 kernel, known-passing): used if ws_size too small.
// =================================================================

__device__ __forceinline__ v8bf cvt8(const float* p){
  const v4u a = *reinterpret_cast<const v4u*>(p);
  const v4u b = *reinterpret_cast<const v4u*>(p + 4);
  v8bf r;
  #pragma unroll
  for (int i=0;i<4;i++){ r[i]   = (short)(a[i] >> 16); }
  #pragma unroll
  for (int i=0;i<4;i++){ r[4+i] = (short)(b[i] >> 16); }
  return r;
}

__device__ __forceinline__ void gbar_f(u32* bar, int leaf, u32 target){
  __syncthreads();
  if (threadIdx.x == 0){
    __threadfence();
    u32 lf = __hip_atomic_fetch_add(&bar[leaf*32], 1u, __ATOMIC_SEQ_CST, SC);
    if (lf == 31u){
      u32 rt = __hip_atomic_fetch_add(&bar[256], 1u, __ATOMIC_SEQ_CST, SC);
      if (rt == 7u){
        #pragma unroll
        for (int i=0;i<8;i++) __hip_atomic_store(&bar[i*32], 0u, __ATOMIC_RELAXED, SC);
        __hip_atomic_store(&bar[256], 0u, __ATOMIC_RELAXED, SC);
        __hip_atomic_fetch_add(&bar[288], 1u, __ATOMIC_SEQ_CST, SC);
      }
    }
    while (__hip_atomic_load(&bar[288], __ATOMIC_SEQ_CST, SC) < target){
      __builtin_amdgcn_s_sleep(2);
    }
    __threadfence();
  }
  __syncthreads();
}

__global__ void init_f32(u32* __restrict__ bar, float* __restrict__ h3,
                         float* __restrict__ comp, const float* __restrict__ x){
  int tid = blockIdx.x*256 + threadIdx.x;
  if (tid < 1024) bar[tid] = 0u;
  if (tid < 16384) comp[tid] = x[(size_t)(tid>>7)*16384 + (tid&127)];
  h3[tid] = 0.f;
}

__device__ __forceinline__ void upper_f32(
    const float* __restrict__ src, float* __restrict__ dst,
    const float* __restrict__ Wih, const float* __restrict__ Whh,
    const float* __restrict__ bih, const float* __restrict__ bhh,
    int j, int rowbase, int wave, int lane, float* smem, float* out_h)
{
  const int l15 = lane & 15, quad = lane >> 4;
  v4f acc0 = {0.f,0.f,0.f,0.f}, acc1 = {0.f,0.f,0.f,0.f};
  const float* a0 = src + (size_t)(rowbase + l15)*1024 + quad*8;
  if (wave < 2){
    const size_t ro = (size_t)(wave*1024 + j*16 + l15)*1024 + quad*8;
    const float* wi = Wih + ro;
    const float* wh = Whh + ro;
    #pragma unroll 2
    for (int kk=0; kk<32; ++kk){
      v8bf af0 = cvt8(a0 + kk*32);
      v8bf af1 = cvt8(a0 + 16*1024 + kk*32);
      v8bf w0  = cvt8(wi + kk*32);
      v8bf w1  = cvt8(wh + kk*32);
      acc0 = __builtin_amdgcn_mfma_f32_16x16x32_bf16(af0, w0, acc0, 0,0,0);
      acc0 = __builtin_amdgcn_mfma_f32_16x16x32_bf16(af0, w1, acc0, 0,0,0);
      acc1 = __builtin_amdgcn_mfma_f32_16x16x32_bf16(af1, w0, acc1, 0,0,0);
      acc1 = __builtin_amdgcn_mfma_f32_16x16x32_bf16(af1, w1, acc1, 0,0,0);
    }
  } else {
    const float* w = (wave == 2 ? Wih : Whh) + (size_t)(2048 + j*16 + l15)*1024 + quad*8;
    #pragma unroll 2
    for (int kk=0; kk<32; ++kk){
      v8bf af0 = cvt8(a0 + kk*32);
      v8bf af1 = cvt8(a0 + 16*1024 + kk*32);
      v8bf w0  = cvt8(w + kk*32);
      acc0 = __builtin_amdgcn_mfma_f32_16x16x32_bf16(af0, w0, acc0, 0,0,0);
      acc1 = __builtin_amdgcn_mfma_f32_16x16x32_bf16(af1, w0, acc1, 0,0,0);
    }
  }
  #pragma unroll
  for (int r=0;r<4;r++){
    smem[((wave*32) + quad*4 + r)*16 + l15]      = acc0[r];
    smem[((wave*32) + 16 + quad*4 + r)*16 + l15] = acc1[r];
  }
  __syncthreads();
  const int tid = threadIdx.x;
  for (int e = tid; e < 512; e += 256){
    int rl = e>>4, c = e&15;
    int row = rowbase + rl, col = j*16 + c;
    float pr  = smem[(0*32+rl)*16+c] + bih[col]      + bhh[col];
    float pz  = smem[(1*32+rl)*16+c] + bih[1024+col] + bhh[1024+col];
    float pin = smem[(2*32+rl)*16+c] + bih[2048+col];
    float phn = smem[(3*32+rl)*16+c] + bhh[2048+col];
    float rg = sigm(pr);
    float zg = sigm(pz);
    float nv = tanh_(pin + rg*phn);
    float hp = src[(size_t)row*1024 + col];
    float hv = (1.f - zg)*nv + zg*hp;
    dst[(size_t)row*1024 + col] = hv;
    if (out_h) out_h[(size_t)row*1024 + col] = hv;
  }
}

__global__ __launch_bounds__(256, 1) void gru_f32(
  const float* __restrict__ x, const float* __restrict__ masks,
  const float* __restrict__ Wih0, const float* __restrict__ Whh0,
  const float* __restrict__ bih0, const float* __restrict__ bhh0,
  const float* __restrict__ WihR, const float* __restrict__ WhhR,
  const float* __restrict__ bihR, const float* __restrict__ bhhR,
  const float* __restrict__ Wp,   const float* __restrict__ bp,
  float* hA, float* hB, float* hC, float* comp,
  u32* bar, float* out)
{
  const int tid  = threadIdx.x;
  const int lane = tid & 63;
  const int wave = tid >> 6;
  const int l15  = lane & 15;
  const int quad = lane >> 4;
  const int bid  = blockIdx.x;
  const int leaf = bid & 7;
  const int slot = bid >> 3;
  const int j    = leaf*8 + (slot >> 2);
  const int rowbase = (slot & 3) * 32;
  __shared__ float smem[6*32*16];
  u32 bc = 0;

  #pragma unroll 1
  for (int t = 0; t < 128; ++t){
    {
      if (wave < 3){
        v4f acc0 = {0.f,0.f,0.f,0.f}, acc1 = {0.f,0.f,0.f,0.f};
        const float* w  = Whh0 + (size_t)(wave*1024 + j*16 + l15)*1024 + quad*8;
        const float* a0 = hA + (size_t)(rowbase + l15)*1024 + quad*8;
        #pragma unroll 2
        for (int kk=0; kk<32; ++kk){
          v8bf af0 = cvt8(a0 + kk*32);
          v8bf af1 = cvt8(a0 + 16*1024 + kk*32);
          v8bf w0  = cvt8(w + kk*32);
          acc0 = __builtin_amdgcn_mfma_f32_16x16x32_bf16(af0, w0, acc0, 0,0,0);
          acc1 = __builtin_amdgcn_mfma_f32_16x16x32_bf16(af1, w0, acc1, 0,0,0);
        }
        #pragma unroll
        for (int r=0;r<4;r++){
          smem[((wave*32) + quad*4 + r)*16 + l15]      = acc0[r];
          smem[((wave*32) + 16 + quad*4 + r)*16 + l15] = acc1[r];
        }
      } else {
        v4f ax[3][2];
        #pragma unroll
        for (int g=0;g<3;g++){ ax[g][0] = (v4f){0.f,0.f,0.f,0.f}; ax[g][1] = (v4f){0.f,0.f,0.f,0.f}; }
        const float* a0 = comp + (size_t)(rowbase + l15)*128 + quad*8;
        #pragma unroll
        for (int kk=0; kk<4; ++kk){
          v8bf af0 = cvt8(a0 + kk*32);
          v8bf af1 = cvt8(a0 + 16*128 + kk*32);
          #pragma unroll
          for (int g=0; g<3; ++g){
            v8bf w0 = cvt8(Wih0 + (size_t)(g*1024 + j*16 + l15)*128 + quad*8 + kk*32);
            ax[g][0] = __builtin_amdgcn_mfma_f32_16x16x32_bf16(af0, w0, ax[g][0], 0,0,0);
            ax[g][1] = __builtin_amdgcn_mfma_f32_16x16x32_bf16(af1, w0, ax[g][1], 0,0,0);
          }
        }
        #pragma unroll
        for (int g=0; g<3; ++g){
          #pragma unroll
          for (int r=0;r<4;r++){
            smem[(((3+g)*32) + quad*4 + r)*16 + l15]      = ax[g][0][r];
            smem[(((3+g)*32) + 16 + quad*4 + r)*16 + l15] = ax[g][1][r];
          }
        }
      }
      __syncthreads();
      for (int e = tid; e < 512; e += 256){
        int rl = e>>4, c = e&15;
        int row = rowbase + rl, col = j*16 + c;
        float gh_r = smem[(0*32+rl)*16+c] + bhh0[col];
        float gh_z = smem[(1*32+rl)*16+c] + bhh0[1024+col];
        float gh_n = smem[(2*32+rl)*16+c] + bhh0[2048+col];
        float gi_r = smem[(3*32+rl)*16+c] + bih0[col];
        float gi_z = smem[(4*32+rl)*16+c] + bih0[1024+col];
        float gi_n = smem[(5*32+rl)*16+c] + bih0[2048+col];
        float rg = sigm(gi_r + gh_r);
        float zg = sigm(gi_z + gh_z);
        float nv = tanh_(gi_n + rg*gh_n);
        float hp = hA[(size_t)row*1024 + col];
        hB[(size_t)row*1024 + col] = (1.f - zg)*nv + zg*hp;
      }
      gbar_f(bar, leaf, ++bc);
    }
    upper_f32(hB, hC, WihR, WhhR, bihR, bhhR, j, rowbase, wave, lane, smem, nullptr);
    gbar_f(bar, leaf, ++bc);
    upper_f32(hC, hA, WihR + 3145728, WhhR + 3145728, bihR + 3072, bhhR + 3072,
              j, rowbase, wave, lane, smem, (t == 127) ? out : nullptr);
    gbar_f(bar, leaf, ++bc);
    if (t != 127){
      if (bid < 32){
        const int jj  = bid >> 2;
        const int rb2 = (bid & 3) * 32;
        v4f p0 = {0.f,0.f,0.f,0.f}, p1 = {0.f,0.f,0.f,0.f};
        const float* a0 = hA + (size_t)(rb2 + l15)*1024 + wave*256 + quad*8;
        const float* wp = Wp + (size_t)(jj*16 + l15)*1024 + wave*256 + quad*8;
        #pragma unroll
        for (int i=0;i<8;i++){
          v8bf wf  = cvt8(wp + i*32);
          v8bf af0 = cvt8(a0 + i*32);
          v8bf af1 = cvt8(a0 + 16*1024 + i*32);
          p0 = __builtin_amdgcn_mfma_f32_16x16x32_bf16(af0, wf, p0, 0,0,0);
          p1 = __builtin_amdgcn_mfma_f32_16x16x32_bf16(af1, wf, p1, 0,0,0);
        }
        #pragma unroll
        for (int r=0;r<4;r++){
          smem[((wave*32) + quad*4 + r)*16 + l15]      = p0[r];
          smem[((wave*32) + 16 + quad*4 + r)*16 + l15] = p1[r];
        }
        __syncthreads();
        for (int e = tid; e < 512; e += 256){
          int rl = e>>4, c = e&15;
          int row = rb2 + rl, d = jj*16 + c;
          float imp = smem[(0*32+rl)*16+c] + smem[(1*32+rl)*16+c]
                    + smem[(2*32+rl)*16+c] + smem[(3*32+rl)*16+c] + bp[d];
          float m  = masks[row*128 + t];
          float xv = x[((size_t)row*128 + t)*128 + d];
          float cv = m*xv + (1.f - m)*imp;
          size_t o = ((size_t)row*127 + t)*128 + d;
          out[131072 + o]  = cv;
          out[2211840 + o] = imp;
          comp[row*128 + d] = cv;
        }
      }
      gbar_f(bar, leaf, ++bc);
    }
  }
}

// ---------------- host ----------------
extern "C" void kernel_launch(void* const* d_in, const int* in_sizes, int n_in,
                              void* d_out, int out_size, void* d_ws, size_t ws_size,
                              hipStream_t stream)
{
  (void)in_sizes; (void)n_in; (void)out_size;
  const float* x     = (const float*)d_in[0];
  const float* masks = (const float*)d_in[1];
  const float* Wih0  = (const float*)d_in[2];
  const float* Whh0  = (const float*)d_in[3];
  const float* bih0  = (const float*)d_in[4];
  const float* bhh0  = (const float*)d_in[5];
  const float* WihR  = (const float*)d_in[6];
  const float* WhhR  = (const float*)d_in[7];
  const float* bihR  = (const float*)d_in[8];
  const float* bhhR  = (const float*)d_in[9];
  const float* Wp    = (const float*)d_in[10];
  const float* bp    = (const float*)d_in[11];
  float* out = (float*)d_out;

  const size_t NEED = 24940544;   // bar + bf16 h/comp + packed weights
  if (ws_size >= NEED){
    u32*  bar     = (u32*)d_ws;
    bf16* hA      = (bf16*)((char*)d_ws + 4096);
    bf16* hB      = hA + 131072;
    bf16* hC      = hB + 131072;
    bf16* comp    = hC + 131072;
    bf16* packU   = comp + 16384;        // 2*4*1024*1024 elems
    bf16* packL0h = packU + 8388608;     // 3*1024*1024
    bf16* packL0x = packL0h + 3145728;   // 3*1024*128
    bf16* packImp = packL0x + 393216;    // 128*1024

    hipLaunchKernelGGL(init_pk,      dim3(1536), dim3(256), 0, stream, bar, hA, comp, x);
    hipLaunchKernelGGL(pack_upper_k, dim3(4096), dim3(256), 0, stream, WihR, WhhR, packU);
    hipLaunchKernelGGL(pack_l0h_k,   dim3(1536), dim3(256), 0, stream, Whh0, packL0h);
    hipLaunchKernelGGL(pack_l0x_k,   dim3(192),  dim3(256), 0, stream, Wih0, packL0x);
    hipLaunchKernelGGL(pack_imp_k,   dim3(64),   dim3(256), 0, stream, Wp, packImp);
    hipLaunchKernelGGL(gru_pk,       dim3(256),  dim3(1024), 0, stream,
        x, masks, bih0, bhh0, bihR, bhhR, bp,
        packU, packL0h, packL0x, packImp, hA, hB, hC, comp, bar, out);
  } else {
    u32*   bar  = (u32*)d_ws;
    float* hA   = (float*)((char*)d_ws + 4096);
    float* hB   = hA + 131072;
    float* hC   = hB + 131072;
    float* comp = hC + 131072;
    hipLaunchKernelGGL(init_f32, dim3(1536), dim3(256), 0, stream, bar, hA, comp, x);
    hipLaunchKernelGGL(gru_f32,  dim3(256),  dim3(256), 0, stream,
        x, masks, Wih0, Whh0, bih0, bhh0, WihR, WhhR, bihR, bhhR, Wp, bp,
        hA, hB, hC, comp, bar, out);
  }
}

// Round 5
// 5006.425 us; speedup vs baseline: 5.3620x; 2.0644x over previous
//
#include <hip/hip_runtime.h>
#include <hip/hip_bf16.h>

// GRU-imputation scan (B=128,T=128,D=128,H=1024,L=3), f32 in/out.
// Round 5: 4 independent row-groups (32 rows each) x 32 blocks; per-group
// relaxed-atomic barrier with NO cache maintenance. Cross-block state (h,
// comp) moves via device-coherent sc0+sc1 loads/stores (LLC), staged into
// fragment-ordered LDS once per phase. Weights stay L2-resident (packed
// bf16, r/z pre-summed for upper layers).

typedef __hip_bfloat16 bf16;
typedef unsigned int u32;
typedef unsigned short u16;
typedef __attribute__((ext_vector_type(8))) short v8bf;   // 8 x bf16 (16B)
typedef __attribute__((ext_vector_type(4))) float v4f;    // MFMA C/D
typedef __attribute__((ext_vector_type(4))) u32 v4u;

#define SC __HIP_MEMORY_SCOPE_AGENT

__device__ __forceinline__ float bf2f(bf16 v){ return __bfloat162float(v); }
__device__ __forceinline__ bf16 f2bf(float v){ return __float2bfloat16(v); }
__device__ __forceinline__ float sigm(float x){ return 1.f/(1.f + __expf(-x)); }
__device__ __forceinline__ float tanh_(float x){
  float a = fminf(fmaxf(x, -15.f), 15.f);
  float t = __expf(2.f*a);
  return (t-1.f)/(t+1.f);
}
__device__ __forceinline__ v8bf ldv(const bf16* p){ return *reinterpret_cast<const v8bf*>(p); }
__device__ __forceinline__ void vdrain(){ asm volatile("s_waitcnt vmcnt(0)" ::: "memory"); }

// ---- device-coherent (LLC) accesses: bypass L1+L2 via sc0 sc1 ----
__device__ __forceinline__ void ldx4_coh(const bf16* p0, const bf16* p1,
                                         const bf16* p2, const bf16* p3,
                                         v4u& r0, v4u& r1, v4u& r2, v4u& r3){
  asm volatile(
    "global_load_dwordx4 %0, %4, off sc0 sc1\n\t"
    "global_load_dwordx4 %1, %5, off sc0 sc1\n\t"
    "global_load_dwordx4 %2, %6, off sc0 sc1\n\t"
    "global_load_dwordx4 %3, %7, off sc0 sc1\n\t"
    "s_waitcnt vmcnt(0)"
    : "=&v"(r0), "=&v"(r1), "=&v"(r2), "=&v"(r3)
    : "v"(p0), "v"(p1), "v"(p2), "v"(p3)
    : "memory");
}
__device__ __forceinline__ v4u ldx1_coh(const bf16* p){
  v4u r;
  asm volatile("global_load_dwordx4 %0, %1, off sc0 sc1\n\ts_waitcnt vmcnt(0)"
               : "=&v"(r) : "v"(p) : "memory");
  return r;
}
__device__ __forceinline__ void st2_coh(bf16* p, bf16 v){
  u32 vv = (u32)__builtin_bit_cast(u16, v);
  asm volatile("global_store_short %0, %1, off sc0 sc1" :: "v"(p), "v"(vv) : "memory");
}

// ---- per-group barrier: 32 arrivals, relaxed atomics, no cache ops ----
__device__ __forceinline__ void gbar2(u32* ctr, u32* ep, u32 target){
  __syncthreads();
  if (threadIdx.x == 0){
    vdrain();                                        // all coherent stores at LLC
    u32 a = __hip_atomic_fetch_add(ctr, 1u, __ATOMIC_RELAXED, SC);
    if (a == 31u){
      __hip_atomic_store(ctr, 0u, __ATOMIC_RELAXED, SC);
      vdrain();                                      // reset visible before epoch++
      __hip_atomic_fetch_add(ep, 1u, __ATOMIC_RELAXED, SC);
    }
    while (__hip_atomic_load(ep, __ATOMIC_RELAXED, SC) < target){
      __builtin_amdgcn_s_sleep(1);
    }
  }
  __syncthreads();
}

// =================================================================
// Packing kernels (unchanged from round 4; validated).
// Fragment unit = 64 lanes x 8 bf16; lane's 8 elems =
//   W[row(j,lane&15)][kk*32 + ((lane>>4)&3)*8 + e]
// =================================================================
__global__ void pack_upper_k(const float* __restrict__ Wih, const float* __restrict__ Whh,
                             bf16* __restrict__ dst){
  int tid = blockIdx.x*256 + threadIdx.x;          // 1,048,576
  int lane = tid & 63;
  int u    = tid >> 6;
  int kk   = u & 31;
  int j    = (u >> 5) & 63;
  int s    = (u >> 11) & 3;
  int l    = u >> 13;
  int n    = j*16 + (lane & 15);
  int k    = kk*32 + ((lane>>4)&3)*8;
  int row  = (s==0) ? n : (s==1 ? 1024+n : 2048+n);
  size_t src = ((size_t)l*3072 + row)*1024 + k;
  size_t o = (size_t)tid*8;
  #pragma unroll
  for (int e=0;e<8;e++){
    float v;
    if (s < 2)      v = Wih[src+e] + Whh[src+e];
    else if (s==2)  v = Wih[src+e];
    else            v = Whh[src+e];
    dst[o+e] = f2bf(v);
  }
}
__global__ void pack_l0h_k(const float* __restrict__ Whh0, bf16* __restrict__ dst){
  int tid = blockIdx.x*256 + threadIdx.x;          // 393,216
  int lane = tid & 63;
  int u  = tid >> 6;
  int kk = u & 31;
  int j  = (u >> 5) & 63;
  int g  = u >> 11;
  int row = g*1024 + j*16 + (lane&15);
  int k   = kk*32 + ((lane>>4)&3)*8;
  size_t src = (size_t)row*1024 + k;
  size_t o = (size_t)tid*8;
  #pragma unroll
  for (int e=0;e<8;e++) dst[o+e] = f2bf(Whh0[src+e]);
}
__global__ void pack_l0x_k(const float* __restrict__ Wih0, bf16* __restrict__ dst){
  int tid = blockIdx.x*256 + threadIdx.x;          // 49,152
  int lane = tid & 63;
  int u  = tid >> 6;
  int kk = u & 3;
  int j  = (u >> 2) & 63;
  int g  = u >> 8;
  int row = g*1024 + j*16 + (lane&15);
  int k   = kk*32 + ((lane>>4)&3)*8;
  size_t src = (size_t)row*128 + k;
  size_t o = (size_t)tid*8;
  #pragma unroll
  for (int e=0;e<8;e++) dst[o+e] = f2bf(Wih0[src+e]);
}
__global__ void pack_imp_k(const float* __restrict__ Wp, bf16* __restrict__ dst){
  int tid = blockIdx.x*256 + threadIdx.x;          // 16,384
  int lane = tid & 63;
  int u  = tid >> 6;
  int kk = u & 31;
  int jj = u >> 5;
  int row = jj*16 + (lane&15);
  int k   = kk*32 + ((lane>>4)&3)*8;
  size_t src = (size_t)row*1024 + k;
  size_t o = (size_t)tid*8;
  #pragma unroll
  for (int e=0;e<8;e++) dst[o+e] = f2bf(Wp[src+e]);
}
__global__ void init_pk(u32* __restrict__ bar, bf16* __restrict__ h3,
                        bf16* __restrict__ comp, const float* __restrict__ x){
  int tid = blockIdx.x*256 + threadIdx.x;          // 393,216
  if (tid < 1024) bar[tid] = 0u;
  if (tid < 16384) comp[tid] = f2bf(x[(size_t)(tid>>7)*16384 + (tid&127)]);
  h3[tid] = f2bf(0.f);
}

// =================================================================
// Staging: 32 rows x 1024 cols of h (row stride 1024) -> fragment-ordered
// LDS (64 KB). unit = kk*2 + half (kk=K-chunk 0..31, half=row half).
// chunk-in-unit = lane. Conflict-free ds_write/ds_read.
// =================================================================
__device__ __forceinline__ void stage_h(const bf16* __restrict__ src_rg, bf16* lds_h,
                                        int wave, int lane){
  const int sh = wave & 1, si = (wave >> 1) & 7;
  const int l15 = lane & 15, quad = lane >> 4;
  const bf16* g = src_rg + (size_t)(sh*16 + l15)*1024 + si*32 + quad*8;
  v4u r0,r1,r2,r3;
  ldx4_coh(g, g+256, g+512, g+768, r0,r1,r2,r3);
  bf16* d = lds_h + ((size_t)wave*64 + lane)*8;
  *(v4u*)(d)         = r0;
  *(v4u*)(d + 8192)  = r1;
  *(v4u*)(d + 16384) = r2;
  *(v4u*)(d + 24576) = r3;
}
// A-fragment from staged LDS: rows half*16+l15, K-chunk kk
__device__ __forceinline__ v8bf afrag(const bf16* lds_h, int kk, int ah, int lane){
  return ldv(lds_h + ((size_t)(kk*2+ah)*64 + lane)*8);
}
// scalar element (rl, colh) from staged LDS
__device__ __forceinline__ float hp_lds(const bf16* lds_h, int rl, int colh){
  int kk = colh >> 5, q = (colh >> 3) & 3, e = colh & 7;
  int ah = rl >> 4, lr = rl & 15;
  return bf2f(lds_h[((size_t)(kk*2+ah)*64 + q*16 + lr)*8 + e]);
}

#define MFMA(a,b,c) __builtin_amdgcn_mfma_f32_16x16x32_bf16((a),(b),(c),0,0,0)

// =================================================================
// Main persistent kernel: 128 blocks x 1024 threads (16 waves).
// bid: leaf=bid&7 (XCD affinity for weights), up=bid>>3: rg=up&3 (row group),
// jpair = leaf*4 + (up>>2)  (32 output cols).
// =================================================================
__global__ __launch_bounds__(1024, 4) void gru_pk(
  const float* __restrict__ x, const float* __restrict__ masks,
  const float* __restrict__ bih0, const float* __restrict__ bhh0,
  const float* __restrict__ bihR, const float* __restrict__ bhhR,
  const float* __restrict__ bp,
  const bf16* __restrict__ packU, const bf16* __restrict__ packL0h,
  const bf16* __restrict__ packL0x, const bf16* __restrict__ packImp,
  bf16* hA, bf16* hB, bf16* hC, bf16* comp,
  u32* bar, float* out)
{
  const int tid  = threadIdx.x;
  const int lane = tid & 63;
  const int wave = tid >> 6;           // 0..15
  const int l15  = lane & 15;
  const int quad = lane >> 4;
  const int bid  = blockIdx.x;
  const int leaf = bid & 7;
  const int up   = bid >> 3;           // 0..15
  const int rg   = up & 3;             // row group
  const int jpair= leaf*4 + (up >> 2); // 0..31
  const int rg32 = rg * 32;
  u32* ctr = bar + rg*128;
  u32* ep  = bar + rg*128 + 64;

  __shared__ bf16 lds_h[32768];        // 64 KB staged h slice
  __shared__ bf16 lds_c[4096];         // 8 KB staged comp slice
  __shared__ float lds2[18*512];       // 36 KB pre-activation partials
  u32 bc = 0;

  #pragma unroll 1
  for (int t = 0; t < 128; ++t){
    // ================= L0: hB = GRU0(input=comp, hidden=hA) =================
    {
      stage_h(hA + (size_t)rg32*1024, lds_h, wave, lane);
      if (wave < 8){
        const int sh = wave & 1, skk = wave >> 1;   // comp: K=128, 4 chunks
        const bf16* g = comp + (size_t)(rg32 + sh*16 + l15)*128 + skk*32 + quad*8;
        v4u r = ldx1_coh(g);
        *(v4u*)(lds_c + ((size_t)wave*64 + lane)*8) = r;
      }
      __syncthreads();
      if (wave < 12){
        const int g = wave % 3, jsub = (wave/3) & 1, ksec = wave/6;
        const int j = jpair*2 + jsub;
        v4f a0 = {0.f,0.f,0.f,0.f}, a1 = {0.f,0.f,0.f,0.f};
        const bf16* wp = packL0h + ((size_t)((g*64 + j)*32 + ksec*16))*512 + lane*8;
        #pragma unroll
        for (int i=0;i<16;++i){
          int kk = ksec*16 + i;
          v8bf wf = ldv(wp + (size_t)i*512);
          a0 = MFMA(afrag(lds_h, kk, 0, lane), wf, a0);
          a1 = MFMA(afrag(lds_h, kk, 1, lane), wf, a1);
        }
        #pragma unroll
        for (int r=0;r<4;r++){
          lds2[(wave*32 + quad*4 + r)*16 + l15]      = a0[r];
          lds2[(wave*32 + 16 + quad*4 + r)*16 + l15] = a1[r];
        }
      } else if (wave < 15){
        const int g = wave - 12;
        #pragma unroll
        for (int jsub=0;jsub<2;++jsub){
          const int j = jpair*2 + jsub;
          v4f a0 = {0.f,0.f,0.f,0.f}, a1 = {0.f,0.f,0.f,0.f};
          const bf16* wp = packL0x + ((size_t)((g*64 + j)*4))*512 + lane*8;
          #pragma unroll
          for (int i=0;i<4;++i){
            v8bf wf = ldv(wp + (size_t)i*512);
            a0 = MFMA(ldv(lds_c + ((size_t)(i*2+0)*64 + lane)*8), wf, a0);
            a1 = MFMA(ldv(lds_c + ((size_t)(i*2+1)*64 + lane)*8), wf, a1);
          }
          const int slot = 12 + g*2 + jsub;
          #pragma unroll
          for (int r=0;r<4;r++){
            lds2[(slot*32 + quad*4 + r)*16 + l15]      = a0[r];
            lds2[(slot*32 + 16 + quad*4 + r)*16 + l15] = a1[r];
          }
        }
      }
      __syncthreads();
      {
        const int rl = tid >> 5, c2 = tid & 31;
        const int jsub = c2 >> 4, c = c2 & 15;
        const int col = jpair*32 + c2;
        float ghr = lds2[((0+jsub*3)*32+rl)*16+c] + lds2[((6+jsub*3)*32+rl)*16+c];
        float ghz = lds2[((1+jsub*3)*32+rl)*16+c] + lds2[((7+jsub*3)*32+rl)*16+c];
        float ghn = lds2[((2+jsub*3)*32+rl)*16+c] + lds2[((8+jsub*3)*32+rl)*16+c];
        float gir = lds2[((12+jsub)*32+rl)*16+c];
        float giz = lds2[((14+jsub)*32+rl)*16+c];
        float gin = lds2[((16+jsub)*32+rl)*16+c];
        float rgg = sigm(gir + bih0[col]      + ghr + bhh0[col]);
        float zg  = sigm(giz + bih0[1024+col] + ghz + bhh0[1024+col]);
        float nv  = tanh_(gin + bih0[2048+col] + rgg*(ghn + bhh0[2048+col]));
        float hp  = hp_lds(lds_h, rl, col);
        st2_coh(hB + (size_t)(rg32+rl)*1024 + col, f2bf((1.f - zg)*nv + zg*hp));
        vdrain();
      }
      gbar2(ctr, ep, ++bc);
    }

    // ================= L1 / L2: upper layers =================
    #pragma unroll 1
    for (int lay = 0; lay < 2; ++lay){
      const bf16* src = lay ? hC : hB;
      bf16*       dst = lay ? hA : hC;
      const bf16* packL = packU + (size_t)lay*4194304;
      const float* bi = bihR + lay*3072;
      const float* bh = bhhR + lay*3072;
      float* out_h = (lay == 1 && t == 127) ? out : nullptr;

      stage_h(src + (size_t)rg32*1024, lds_h, wave, lane);
      __syncthreads();
      {
        const int s = wave & 3, jsub = (wave>>2) & 1, ksec = wave >> 3;
        const int j = jpair*2 + jsub;
        v4f a0 = {0.f,0.f,0.f,0.f}, a1 = {0.f,0.f,0.f,0.f};
        const bf16* wp = packL + ((size_t)((s*64 + j)*32 + ksec*16))*512 + lane*8;
        #pragma unroll
        for (int i=0;i<16;++i){
          int kk = ksec*16 + i;
          v8bf wf = ldv(wp + (size_t)i*512);
          a0 = MFMA(afrag(lds_h, kk, 0, lane), wf, a0);
          a1 = MFMA(afrag(lds_h, kk, 1, lane), wf, a1);
        }
        #pragma unroll
        for (int r=0;r<4;r++){
          lds2[(wave*32 + quad*4 + r)*16 + l15]      = a0[r];
          lds2[(wave*32 + 16 + quad*4 + r)*16 + l15] = a1[r];
        }
      }
      __syncthreads();
      {
        const int rl = tid >> 5, c2 = tid & 31;
        const int jsub = c2 >> 4, c = c2 & 15;
        const int col = jpair*32 + c2;
        // slot(s,jsub,ksec) = s + jsub*4 + ksec*8
        float pr  = lds2[((0+jsub*4)*32+rl)*16+c] + lds2[((8+jsub*4)*32+rl)*16+c];
        float pz  = lds2[((1+jsub*4)*32+rl)*16+c] + lds2[((9+jsub*4)*32+rl)*16+c];
        float pin = lds2[((2+jsub*4)*32+rl)*16+c] + lds2[((10+jsub*4)*32+rl)*16+c];
        float phn = lds2[((3+jsub*4)*32+rl)*16+c] + lds2[((11+jsub*4)*32+rl)*16+c];
        float rgg = sigm(pr + bi[col] + bh[col]);
        float zg  = sigm(pz + bi[1024+col] + bh[1024+col]);
        float nv  = tanh_(pin + bi[2048+col] + rgg*(phn + bh[2048+col]));
        float hp  = hp_lds(lds_h, rl, col);
        float hv  = (1.f - zg)*nv + zg*hp;
        st2_coh(dst + (size_t)(rg32+rl)*1024 + col, f2bf(hv));
        if (out_h) out_h[(size_t)(rg32+rl)*1024 + col] = hv;
        vdrain();
      }
      gbar2(ctr, ep, ++bc);
    }

    // ================= IC: imputed/completed (t < 127) =================
    if (t != 127){
      if ((up >> 2) == 0){               // 8 blocks per group, jj = leaf
        stage_h(hA + (size_t)rg32*1024, lds_h, wave, lane);
        __syncthreads();
        const int jj = leaf;
        v4f a0 = {0.f,0.f,0.f,0.f}, a1 = {0.f,0.f,0.f,0.f};
        const bf16* wp = packImp + ((size_t)(jj*32 + wave*2))*512 + lane*8;
        #pragma unroll
        for (int i=0;i<2;++i){
          int kk = wave*2 + i;
          v8bf wf = ldv(wp + (size_t)i*512);
          a0 = MFMA(afrag(lds_h, kk, 0, lane), wf, a0);
          a1 = MFMA(afrag(lds_h, kk, 1, lane), wf, a1);
        }
        #pragma unroll
        for (int r=0;r<4;r++){
          lds2[(wave*32 + quad*4 + r)*16 + l15]      = a0[r];
          lds2[(wave*32 + 16 + quad*4 + r)*16 + l15] = a1[r];
        }
        __syncthreads();
        if (tid < 512){
          const int rl = tid >> 4, c = tid & 15;
          const int row = rg32 + rl, d = jj*16 + c;
          float imp = bp[d];
          #pragma unroll
          for (int w2=0; w2<16; ++w2) imp += lds2[(w2*32+rl)*16+c];
          float m  = masks[row*128 + t];
          float xv = x[((size_t)row*128 + t)*128 + d];
          float cv = m*xv + (1.f - m)*imp;
          size_t o = ((size_t)row*127 + t)*128 + d;
          out[131072 + o]  = cv;    // completed
          out[2211840 + o] = imp;   // imputed
          st2_coh(comp + (size_t)row*128 + d, f2bf(cv));
          vdrain();
        }
      }
      gbar2(ctr, ep, ++bc);
    }
  }
}

// ---------------- host ----------------
extern "C" void kernel_launch(void* const* d_in, const int* in_sizes, int n_in,
                              void* d_out, int out_size, void* d_ws, size_t ws_size,
                              hipStream_t stream)
{
  (void)in_sizes; (void)n_in; (void)out_size; (void)ws_size;
  const float* x     = (const float*)d_in[0];
  const float* masks = (const float*)d_in[1];
  const float* Wih0  = (const float*)d_in[2];
  const float* Whh0  = (const float*)d_in[3];
  const float* bih0  = (const float*)d_in[4];
  const float* bhh0  = (const float*)d_in[5];
  const float* WihR  = (const float*)d_in[6];
  const float* WhhR  = (const float*)d_in[7];
  const float* bihR  = (const float*)d_in[8];
  const float* bhhR  = (const float*)d_in[9];
  const float* Wp    = (const float*)d_in[10];
  const float* bp    = (const float*)d_in[11];
  float* out = (float*)d_out;

  // ws: bar u32[1024] | hA hB hC (bf16 131072 ea) | comp (bf16 16384) | packed weights
  u32*  bar     = (u32*)d_ws;
  bf16* hA      = (bf16*)((char*)d_ws + 4096);
  bf16* hB      = hA + 131072;
  bf16* hC      = hB + 131072;
  bf16* comp    = hC + 131072;
  bf16* packU   = comp + 16384;        // 8,388,608 elems
  bf16* packL0h = packU + 8388608;     // 3,145,728
  bf16* packL0x = packL0h + 3145728;   // 393,216
  bf16* packImp = packL0x + 393216;    // 131,072

  hipLaunchKernelGGL(init_pk,      dim3(1536), dim3(256), 0, stream, bar, hA, comp, x);
  hipLaunchKernelGGL(pack_upper_k, dim3(4096), dim3(256), 0, stream, WihR, WhhR, packU);
  hipLaunchKernelGGL(pack_l0h_k,   dim3(1536), dim3(256), 0, stream, Whh0, packL0h);
  hipLaunchKernelGGL(pack_l0x_k,   dim3(192),  dim3(256), 0, stream, Wih0, packL0x);
  hipLaunchKernelGGL(pack_imp_k,   dim3(64),   dim3(256), 0, stream, Wp, packImp);
  hipLaunchKernelGGL(gru_pk,       dim3(128),  dim3(1024), 0, stream,
      x, masks, bih0, bhh0, bihR, bhhR, bp,
      packU, packL0h, packL0x, packImp, hA, hB, hC, comp, bar, out);
}